// Round 4
// baseline (138.705 us; speedup 1.0000x reference)
//
#include <hip/hip_runtime.h>

#define BATCH 16
#define HH 512
#define WW 512
#define RSLICE 4
#define NSLICE (HH / RSLICE)   // 128

static constexpr size_t PLANE = (size_t)HH * WW;
static constexpr size_t COLP_ELEMS = (size_t)BATCH * NSLICE * WW; // 1M floats (4 MB)
static constexpr size_t ROWS_ELEMS = (size_t)BATCH * HH;          // 8192 floats

// Per-row register buffer: ref/tgt x 3 channels, 2 columns each (float2, 8B
// loads), plus the boundary column (col 2t+2) scalars for wave-edge lanes.
// Two buffers = 36 floats; total kernel ~70 VGPR -> no spill at default
// allocator budget. (Round 2 lesson: a min-occupancy __launch_bounds__ hint
// clamped VGPR to 64 and spilled 240 B/thread = 31.6 MB scratch WRITE_SIZE.)
struct RowBuf {
  float2 r0, r1, r2, t0, t1, t2;
  float br0, br1, br2, bt0, bt1, bt2;
};

__device__ __forceinline__ void load_row(RowBuf& B, const float* __restrict__ rb,
                                         const float* __restrict__ tb, int row,
                                         int t, bool bnd) {
  const size_t o = (size_t)row * WW + 2 * t;
  B.r0 = *(const float2*)(rb + o);
  B.r1 = *(const float2*)(rb + o + PLANE);
  B.r2 = *(const float2*)(rb + o + 2 * PLANE);
  B.t0 = *(const float2*)(tb + o);
  B.t1 = *(const float2*)(tb + o + PLANE);
  B.t2 = *(const float2*)(tb + o + 2 * PLANE);
  if (bnd) {
    const size_t ob = o + 2;
    B.br0 = rb[ob]; B.br1 = rb[ob + PLANE]; B.br2 = rb[ob + 2 * PLANE];
    B.bt0 = tb[ob]; B.bt1 = tb[ob + PLANE]; B.bt2 = tb[ob + 2 * PLANE];
  }
}

__device__ __forceinline__ float lum3(float a, float b, float c) {
  return 0.299f * a + 0.587f * b + 0.114f * c;
}

// Kernel A: block = (batch, 4-row slice); 256 threads, thread owns cols
// 2t, 2t+1. Grid = 16*128 = 2048 blocks x 4 waves = 8 blocks/CU -> ~28
// waves/CU resident (TLP is what hides the ~900cy HBM latency; r2/r3 showed
// BW scales ~linearly with wave count: 6 waves->1.7 TB/s, 16->~2.8 TB/s).
// Halo row r0+4 is re-read by the next slice, but the 100.7 MB input is
// L3-resident so halos cost L3 hits, not HBM fetch. Fully-unrolled 5-row
// loop, alternating named buffers X/Y, prefetch distance 2 rows.
__global__ __launch_bounds__(256) void jbd_reduce(const float* __restrict__ ref,
                                                  const float* __restrict__ tgt,
                                                  float* __restrict__ colp,
                                                  float* __restrict__ rows) {
  const int t = threadIdx.x;          // 0..255
  const int lane = t & 63;
  const int wid = t >> 6;
  const bool bnd = (lane == 63) && (t != 255);  // needs next wave's col 2t+2
  const int slice = blockIdx.x & (NSLICE - 1);
  const int b = blockIdx.x >> 7;      // / NSLICE
  const int r0 = slice * RSLICE;
  const float* rb = ref + (size_t)b * 3 * PLANE;
  const float* tb = tgt + (size_t)b * 3 * PLANE;
  __shared__ float rowpart[RSLICE][4];

  float ca0 = 0.f, ca1 = 0.f;                     // per-column de_h sums
  float plr0 = 0.f, plr1 = 0.f, plt0 = 0.f, plt1 = 0.f;  // prev-row lums

  RowBuf X, Y;
  load_row(X, rb, tb, r0, t, bnd);
  load_row(Y, rb, tb, r0 + 1, t, bnd);   // r0+1 <= 509, always valid

#pragma unroll
  for (int i = 0; i <= RSLICE; ++i) {
    RowBuf& C = (i & 1) ? Y : X;         // i is unroll-constant -> static
    const float a0 = lum3(C.r0.x, C.r1.x, C.r2.x);
    const float a1 = lum3(C.r0.y, C.r1.y, C.r2.y);
    const float c0 = lum3(C.t0.x, C.t1.x, C.t2.x);
    const float c1 = lum3(C.t0.y, C.t1.y, C.t2.y);
    float blr = 0.f, blt = 0.f;
    if (bnd) {
      blr = lum3(C.br0, C.br1, C.br2);
      blt = lum3(C.bt0, C.bt1, C.bt2);
    }
    // prefetch row r0+i+2 into the buffer just consumed (regs now free)
    if (i + 2 <= RSLICE)
      load_row(C, rb, tb, min(r0 + i + 2, HH - 1), t, bnd);
    // horizontal neighbor (col 2t+2) luminance via next lane's col 0
    float nlr = __shfl_down(a0, 1);
    float nlt = __shfl_down(c0, 1);
    if (bnd) { nlr = blr; nlt = blt; }
    if (i < RSLICE) {                    // de_h for this block's own rows
      ca0 += fmaxf(fabsf(c0 - c1) - fabsf(a0 - a1), 0.f);
      if (t < 255)                       // col 511 has no de_h
        ca1 += fmaxf(fabsf(c1 - nlt) - fabsf(a1 - nlr), 0.f);
    }
    if (i >= 1 && (r0 + i) < HH) {       // de_v for row r0+i-1
      float dv = fmaxf(fabsf(c0 - plt0) - fabsf(a0 - plr0), 0.f)
               + fmaxf(fabsf(c1 - plt1) - fabsf(a1 - plr1), 0.f);
      dv += __shfl_xor(dv, 1);
      dv += __shfl_xor(dv, 2);
      dv += __shfl_xor(dv, 4);
      dv += __shfl_xor(dv, 8);
      dv += __shfl_xor(dv, 16);
      dv += __shfl_xor(dv, 32);
      if (lane == 0) rowpart[i - 1][wid] = dv;
    }
    plr0 = a0; plr1 = a1; plt0 = c0; plt1 = c1;
  }
  __syncthreads();
  if (t < RSLICE) {
    const int h = r0 + t;
    if (h < HH - 1)                      // de_v rows are 0..510
      rows[(size_t)b * HH + h] =
          rowpart[t][0] + rowpart[t][1] + rowpart[t][2] + rowpart[t][3];
  }
  *(float2*)&colp[((size_t)b * NSLICE + slice) * WW + 2 * t] =
      make_float2(ca0, ca1);
}

// Kernel B: block per (direction, batch), 64 threads. Thread t owns the 8
// consecutive lines 8t..8t+7 (phase = j directly). float4 loads, per-phase
// butterfly reduce, then uniform 8-way argmax (strict > = first-index ties).
__global__ __launch_bounds__(64) void jbd_phase(const float* __restrict__ colp,
                                                const float* __restrict__ rows,
                                                int* __restrict__ results) {
  const int dir = blockIdx.x & 1;   // 0 = columns (de_h), 1 = rows (de_v)
  const int b = blockIdx.x >> 1;
  const int t = threadIdx.x;        // 0..63
  float c0 = 0.f, c1 = 0.f, c2 = 0.f, c3 = 0.f;
  float c4 = 0.f, c5 = 0.f, c6 = 0.f, c7 = 0.f;
  if (dir == 0) {
#pragma unroll 4
    for (int sl = 0; sl < NSLICE; ++sl) {
      const float* p = colp + ((size_t)b * NSLICE + sl) * WW + 8 * t;
      const float4 u = *(const float4*)p;
      const float4 v = *(const float4*)(p + 4);
      c0 += u.x; c1 += u.y; c2 += u.z; c3 += u.w;
      c4 += v.x; c5 += v.y; c6 += v.z; c7 += v.w;
    }
  } else {
    const float* p = rows + (size_t)b * HH + 8 * t;
    const float4 u = *(const float4*)p;
    const float4 v = *(const float4*)(p + 4);
    c0 = u.x; c1 = u.y; c2 = u.z; c3 = u.w;
    c4 = v.x; c5 = v.y; c6 = v.z; c7 = v.w;
  }
  if (t == 63) c7 = 0.f;            // line 511 does not exist (511 lines)
  float ps[8] = {c0, c1, c2, c3, c4, c5, c6, c7};
  float tot = 0.f;
#pragma unroll
  for (int p = 0; p < 8; ++p) {
    float v = ps[p];
    v += __shfl_xor(v, 1);
    v += __shfl_xor(v, 2);
    v += __shfl_xor(v, 4);
    v += __shfl_xor(v, 8);
    v += __shfl_xor(v, 16);
    v += __shfl_xor(v, 32);
    v *= (1.0f / 512.0f);           // line-mean divisor (H resp. W = 512)
    ps[p] = v;
    tot += v;
  }
  float best = -1.f;
  int bk = 0;
#pragma unroll
  for (int p = 0; p < 8; ++p) {
    const float cnt = (p == 7) ? 63.f : 64.f;  // phases 0..6 -> 64 lines, 7 -> 63
    const float a_k = ps[p] / cnt;
    const float bg = (tot - ps[p]) / (511.f - cnt);
    const float r = a_k / (bg + 1e-8f);
    if (r > best) { best = r; bk = p; }
  }
  if (t == 0) {
    results[4 * b + 2 * dir] = bk;
    results[4 * b + 2 * dir + 1] = (best > (float)(1.0 / 0.35)) ? 1 : 0;
  }
}

// Kernel C: broadcast per-batch decisions to the (B,1,H,W) mask, float4 stores.
__global__ __launch_bounds__(256) void jbd_write(const int* __restrict__ results,
                                                 float* __restrict__ out) {
  const int idx = blockIdx.x * 256 + threadIdx.x;  // float4 index
  const int b = idx >> 16;          // 512*128 float4 per batch
  const int rem = idx & 65535;
  const int h = rem >> 7;
  const int wq = rem & 127;
  const int4 rs = ((const int4*)results)[b];  // {bk_h, blocked_h, bk_v, blocked_v}
  const bool rowm = (rs.w != 0) && ((h & 7) == rs.z) && (h < HH - 1);
  float4 o;
  float* po = (float*)&o;
  const int w0 = wq << 2;
#pragma unroll
  for (int j = 0; j < 4; ++j) {
    const int w = w0 + j;
    const bool colm = (rs.y != 0) && ((w & 7) == rs.x) && (w < WW - 1);
    po[j] = (rowm || colm) ? 1.0f : 0.0f;
  }
  ((float4*)out)[idx] = o;
}

extern "C" void kernel_launch(void* const* d_in, const int* in_sizes, int n_in,
                              void* d_out, int out_size, void* d_ws, size_t ws_size,
                              hipStream_t stream) {
  (void)in_sizes; (void)n_in; (void)out_size; (void)ws_size;
  const float* ref = (const float*)d_in[0];
  const float* tgt = (const float*)d_in[1];
  float* colp = (float*)d_ws;                 // [B][NSLICE][W]
  float* rows = colp + COLP_ELEMS;            // [B][H] (index 511 unused)
  int* results = (int*)(rows + ROWS_ELEMS);   // [B][4]
  jbd_reduce<<<BATCH * NSLICE, 256, 0, stream>>>(ref, tgt, colp, rows);
  jbd_phase<<<2 * BATCH, 64, 0, stream>>>(colp, rows, results);
  jbd_write<<<(BATCH * HH * WW / 4) / 256, 256, 0, stream>>>(results, (float*)d_out);
}

// Round 5
// 136.644 us; speedup vs baseline: 1.0151x; 1.0151x over previous
//
#include <hip/hip_runtime.h>

#define BATCH 16
#define HH 512
#define WW 512
#define RSLICE 8
#define NSLICE (HH / RSLICE)   // 64

static constexpr size_t PLANE = (size_t)HH * WW;
static constexpr size_t COLP_ELEMS = (size_t)BATCH * NSLICE * WW; // 524288 floats (2 MB)
static constexpr size_t ROWS_ELEMS = (size_t)BATCH * HH;          // 8192 floats

__device__ __forceinline__ float lum3(float a, float b, float c) {
  return 0.299f * a + 0.587f * b + 0.114f * c;
}

// Kernel A, LDS-luminance design. Block = (batch, 8-row slice), 256 threads.
// Pass 1: thread t (image g=t>>7, col group u=t&127) computes luminance for
// rows r0..r0+8, cols 4u..4u+3 directly into LDS: 27 INDEPENDENT float4
// loads/thread (no inter-row dependency chain -- rounds 2-4 showed the
// 2-row-prefetch register pipeline throttles issue; MLP here hides HBM
// latency within each wave). Pass 2: de_h/de_v from LDS lums (8B reads,
// 2-way bank aliasing = free). LDS 36.9 KB -> 4 blocks/CU = 16 waves/CU.
__global__ __launch_bounds__(256) void jbd_reduce(const float* __restrict__ ref,
                                                  const float* __restrict__ tgt,
                                                  float* __restrict__ colp,
                                                  float* __restrict__ rows) {
  const int t = threadIdx.x;          // 0..255
  const int lane = t & 63;
  const int wid = t >> 6;
  const int slice = blockIdx.x & (NSLICE - 1);
  const int b = blockIdx.x >> 6;      // / NSLICE
  const int r0 = slice * RSLICE;
  __shared__ float Lr[RSLICE + 1][WW];   // ref luminance rows r0..r0+8
  __shared__ float Lt[RSLICE + 1][WW];   // tgt luminance
  __shared__ float rowpart[RSLICE][4];

  // ---- Pass 1: luminance -> LDS ----
  {
    const int g = t >> 7;             // 0 = ref, 1 = tgt
    const int u = t & 127;            // cols 4u..4u+3
    const float* base = (g ? tgt : ref) + (size_t)b * 3 * PLANE;
    float* L = g ? &Lt[0][0] : &Lr[0][0];
#pragma unroll
    for (int k = 0; k <= RSLICE; ++k) {
      const int row = min(r0 + k, HH - 1);   // slice 63 dup of row 511: unread
      const size_t o = (size_t)row * WW + 4 * u;
      const float4 p0 = *(const float4*)(base + o);
      const float4 p1 = *(const float4*)(base + o + PLANE);
      const float4 p2 = *(const float4*)(base + o + 2 * PLANE);
      float4 l;
      l.x = lum3(p0.x, p1.x, p2.x);
      l.y = lum3(p0.y, p1.y, p2.y);
      l.z = lum3(p0.z, p1.z, p2.z);
      l.w = lum3(p0.w, p1.w, p2.w);
      *(float4*)&L[k * WW + 4 * u] = l;
    }
  }
  __syncthreads();

  // ---- Pass 2: diffs + reductions. Thread t owns cols 2t, 2t+1. ----
  float ca0 = 0.f, ca1 = 0.f;
  const int c0i = 2 * t;
  float lr0 = Lr[0][c0i], lr1 = Lr[0][c0i + 1];
  float lt0 = Lt[0][c0i], lt1 = Lt[0][c0i + 1];
#pragma unroll
  for (int i = 0; i < RSLICE; ++i) {
    // de_h for row r0+i (neighbor col 2t+2; t==255 has no col 512 -> guarded;
    // the read itself stays in-bounds: Lr[i][512] aliases Lr[i+1][0])
    const float nlr = Lr[i][c0i + 2];
    const float nlt = Lt[i][c0i + 2];
    ca0 += fmaxf(fabsf(lt0 - lt1) - fabsf(lr0 - lr1), 0.f);
    if (t < 255)
      ca1 += fmaxf(fabsf(lt1 - nlt) - fabsf(lr1 - nlr), 0.f);
    // de_v row h = r0+i uses lum rows h, h+1
    const float xr0 = Lr[i + 1][c0i], xr1 = Lr[i + 1][c0i + 1];
    const float xt0 = Lt[i + 1][c0i], xt1 = Lt[i + 1][c0i + 1];
    float dv = 0.f;
    if (r0 + i < HH - 1) {               // block-uniform guard (h<=510 valid)
      dv = fmaxf(fabsf(xt0 - lt0) - fabsf(xr0 - lr0), 0.f)
         + fmaxf(fabsf(xt1 - lt1) - fabsf(xr1 - lr1), 0.f);
    }
    dv += __shfl_xor(dv, 1);
    dv += __shfl_xor(dv, 2);
    dv += __shfl_xor(dv, 4);
    dv += __shfl_xor(dv, 8);
    dv += __shfl_xor(dv, 16);
    dv += __shfl_xor(dv, 32);
    if (lane == 0) rowpart[i][wid] = dv;
    lr0 = xr0; lr1 = xr1; lt0 = xt0; lt1 = xt1;
  }
  __syncthreads();
  if (t < RSLICE) {
    const int h = r0 + t;
    if (h < HH - 1)                      // de_v rows are 0..510
      rows[(size_t)b * HH + h] =
          rowpart[t][0] + rowpart[t][1] + rowpart[t][2] + rowpart[t][3];
  }
  *(float2*)&colp[((size_t)b * NSLICE + slice) * WW + c0i] =
      make_float2(ca0, ca1);
}

// Kernel B: block per (direction, batch), 64 threads. Thread t owns the 8
// consecutive lines 8t..8t+7 (phase = j directly). float4 loads, per-phase
// butterfly reduce, then uniform 8-way argmax (strict > = first-index ties).
__global__ __launch_bounds__(64) void jbd_phase(const float* __restrict__ colp,
                                                const float* __restrict__ rows,
                                                int* __restrict__ results) {
  const int dir = blockIdx.x & 1;   // 0 = columns (de_h), 1 = rows (de_v)
  const int b = blockIdx.x >> 1;
  const int t = threadIdx.x;        // 0..63
  float c0 = 0.f, c1 = 0.f, c2 = 0.f, c3 = 0.f;
  float c4 = 0.f, c5 = 0.f, c6 = 0.f, c7 = 0.f;
  if (dir == 0) {
#pragma unroll 4
    for (int sl = 0; sl < NSLICE; ++sl) {
      const float* p = colp + ((size_t)b * NSLICE + sl) * WW + 8 * t;
      const float4 u = *(const float4*)p;
      const float4 v = *(const float4*)(p + 4);
      c0 += u.x; c1 += u.y; c2 += u.z; c3 += u.w;
      c4 += v.x; c5 += v.y; c6 += v.z; c7 += v.w;
    }
  } else {
    const float* p = rows + (size_t)b * HH + 8 * t;
    const float4 u = *(const float4*)p;
    const float4 v = *(const float4*)(p + 4);
    c0 = u.x; c1 = u.y; c2 = u.z; c3 = u.w;
    c4 = v.x; c5 = v.y; c6 = v.z; c7 = v.w;
  }
  if (t == 63) c7 = 0.f;            // line 511 does not exist (511 lines)
  float ps[8] = {c0, c1, c2, c3, c4, c5, c6, c7};
  float tot = 0.f;
#pragma unroll
  for (int p = 0; p < 8; ++p) {
    float v = ps[p];
    v += __shfl_xor(v, 1);
    v += __shfl_xor(v, 2);
    v += __shfl_xor(v, 4);
    v += __shfl_xor(v, 8);
    v += __shfl_xor(v, 16);
    v += __shfl_xor(v, 32);
    v *= (1.0f / 512.0f);           // line-mean divisor (H resp. W = 512)
    ps[p] = v;
    tot += v;
  }
  float best = -1.f;
  int bk = 0;
#pragma unroll
  for (int p = 0; p < 8; ++p) {
    const float cnt = (p == 7) ? 63.f : 64.f;  // phases 0..6 -> 64 lines, 7 -> 63
    const float a_k = ps[p] / cnt;
    const float bg = (tot - ps[p]) / (511.f - cnt);
    const float r = a_k / (bg + 1e-8f);
    if (r > best) { best = r; bk = p; }
  }
  if (t == 0) {
    results[4 * b + 2 * dir] = bk;
    results[4 * b + 2 * dir + 1] = (best > (float)(1.0 / 0.35)) ? 1 : 0;
  }
}

// Kernel C: broadcast per-batch decisions to the (B,1,H,W) mask, float4 stores.
__global__ __launch_bounds__(256) void jbd_write(const int* __restrict__ results,
                                                 float* __restrict__ out) {
  const int idx = blockIdx.x * 256 + threadIdx.x;  // float4 index
  const int b = idx >> 16;          // 512*128 float4 per batch
  const int rem = idx & 65535;
  const int h = rem >> 7;
  const int wq = rem & 127;
  const int4 rs = ((const int4*)results)[b];  // {bk_h, blocked_h, bk_v, blocked_v}
  const bool rowm = (rs.w != 0) && ((h & 7) == rs.z) && (h < HH - 1);
  float4 o;
  float* po = (float*)&o;
  const int w0 = wq << 2;
#pragma unroll
  for (int j = 0; j < 4; ++j) {
    const int w = w0 + j;
    const bool colm = (rs.y != 0) && ((w & 7) == rs.x) && (w < WW - 1);
    po[j] = (rowm || colm) ? 1.0f : 0.0f;
  }
  ((float4*)out)[idx] = o;
}

extern "C" void kernel_launch(void* const* d_in, const int* in_sizes, int n_in,
                              void* d_out, int out_size, void* d_ws, size_t ws_size,
                              hipStream_t stream) {
  (void)in_sizes; (void)n_in; (void)out_size; (void)ws_size;
  const float* ref = (const float*)d_in[0];
  const float* tgt = (const float*)d_in[1];
  float* colp = (float*)d_ws;                 // [B][NSLICE][W]
  float* rows = colp + COLP_ELEMS;            // [B][H] (index 511 unused)
  int* results = (int*)(rows + ROWS_ELEMS);   // [B][4]
  jbd_reduce<<<BATCH * NSLICE, 256, 0, stream>>>(ref, tgt, colp, rows);
  jbd_phase<<<2 * BATCH, 64, 0, stream>>>(colp, rows, results);
  jbd_write<<<(BATCH * HH * WW / 4) / 256, 256, 0, stream>>>(results, (float*)d_out);
}